// Round 1
// 627.885 us; speedup vs baseline: 1.0087x; 1.0087x over previous
//
#include <hip/hip_runtime.h>

#define POOL 14
#define NUM_ROIS 512
#define IMG_H 200
#define IMG_W 200
#define IMG_C 1024
#define NUM_XCD 8

// Clang ext-vector type: supports elementwise arithmetic and is accepted by
// __builtin_nontemporal_store (HIP's float4 struct is not).
typedef float v4f __attribute__((ext_vector_type(4)));

// One block (256 threads) per (roi, py) row: 14 cells, each thread owns 4
// channels (256*4 = 1024 = C). Rows iy0/iy1 are invariant across the row.
// Block index is swizzled so all 14 rows of a ROI land on the same XCD
// (hardware round-robins blockIdx % 8 -> XCD), keeping the ROI's corner
// footprint inside one 4 MiB L2.
//
// Output is written with NON-TEMPORAL stores: it is write-once data (411 MB)
// that otherwise evicts the 164 MB image from the 256 MiB Infinity Cache.
// Streaming the writes past the caches lets the whole image stay L3-resident,
// so cross-ROI re-reads hit L3 instead of HBM.
__global__ __launch_bounds__(256) void roi_row_kernel(
    const float* __restrict__ img,   // (200,200,1024)
    const int*   __restrict__ rois,  // (512,4) x,y,w,h
    float*       __restrict__ out)   // (512,14,14,1024)
{
    const int b   = blockIdx.x;        // 0 .. 512*14-1 = 7167
    const int xcd = b & (NUM_XCD - 1); // which XCD this block lands on
    const int s   = b >> 3;            // 0 .. 895  (per-XCD sequence)
    const int roi_in = s / POOL;       // 0 .. 63
    const int py     = s - roi_in * POOL;
    const int r      = xcd * (NUM_ROIS / NUM_XCD) + roi_in;  // ROI -> one XCD

    const int4 box = ((const int4*)rois)[r];
    const int bx = box.x, by = box.y, bw = box.z, bh = box.w;

    // jnp f32 semantics: s = arange(POOL) * (dim / 14.0f)
    const float stepy = (float)bh / (float)POOL;
    const float stepx = (float)bw / (float)POOL;

    const float sy = (float)py * stepy;
    const int   y0 = (int)floorf(sy);
    const float wy = sy - (float)y0;
    const int y0c = min(max(y0, 0), bh - 1);
    const int y1c = min(max(y0 + 1, 0), bh - 1);

    const float* __restrict__ row0 = img + (size_t)(by + y0c) * IMG_W * IMG_C;
    const float* __restrict__ row1 = img + (size_t)(by + y1c) * IMG_W * IMG_C;

    const int c = threadIdx.x * 4;
    float* __restrict__ orow =
        out + ((size_t)r * (POOL * POOL) + (size_t)py * POOL) * IMG_C + c;

#pragma unroll
    for (int px = 0; px < POOL; ++px) {
        const float sx = (float)px * stepx;
        const int   x0 = (int)floorf(sx);
        const float wx = sx - (float)x0;
        const int x0c = min(max(x0, 0), bw - 1);
        const int x1c = min(max(x0 + 1, 0), bw - 1);
        const int ix0 = bx + x0c;
        const int ix1 = bx + x1c;

        const v4f g00 = *(const v4f*)(row0 + (size_t)ix0 * IMG_C + c);
        const v4f g01 = *(const v4f*)(row0 + (size_t)ix1 * IMG_C + c);
        const v4f g10 = *(const v4f*)(row1 + (size_t)ix0 * IMG_C + c);
        const v4f g11 = *(const v4f*)(row1 + (size_t)ix1 * IMG_C + c);

        const v4f top = g00 + (g01 - g00) * wx;
        const v4f bot = g10 + (g11 - g10) * wx;
        const v4f res = top + (bot - top) * wy;

        __builtin_nontemporal_store(res, (v4f*)(orow + (size_t)px * IMG_C));
    }
}

extern "C" void kernel_launch(void* const* d_in, const int* in_sizes, int n_in,
                              void* d_out, int out_size, void* d_ws, size_t ws_size,
                              hipStream_t stream) {
    const float* img  = (const float*)d_in[0];
    const int*   rois = (const int*)d_in[1];
    float*       out  = (float*)d_out;

    const int num_blocks = NUM_ROIS * POOL;  // 7168
    roi_row_kernel<<<num_blocks, 256, 0, stream>>>(img, rois, out);
}

// Round 2
// 576.524 us; speedup vs baseline: 1.0986x; 1.0891x over previous
//
#include <hip/hip_runtime.h>

#define POOL 14
#define NUM_ROIS 512
#define IMG_H 200
#define IMG_W 200
#define IMG_C 1024
#define NUM_XCD 8
#define ROIS_PER_XCD (NUM_ROIS / NUM_XCD)    // 64
#define ITEMS_PER_XCD (ROIS_PER_XCD * POOL)  // 896
#define XBINS 8
#define NBINS (IMG_H * XBINS)                // 1600
#define BINS_PER_THREAD 7                    // 256*7 = 1792 >= 1600

typedef float v4f __attribute__((ext_vector_type(4)));

// Sort key for a (roi, py) work item: the actual image row it reads,
// plus coarse x position. Items with equal/adjacent keys read overlapping
// image bytes, so scheduling them concurrently makes the shared segments
// L2 hits instead of independent HBM/MALL fetches.
__device__ __forceinline__ int item_key(const int* __restrict__ rois,
                                        int xcd, int i, int* out_code) {
    const int roi_in = i / POOL;
    const int py     = i - roi_in * POOL;
    const int r      = xcd * ROIS_PER_XCD + roi_in;
    const int4 box   = ((const int4*)rois)[r];  // x,y,w,h
    const float stepy = (float)box.w / (float)POOL;
    const float sy    = (float)py * stepy;
    const int y0  = (int)floorf(sy);
    const int y0c = min(max(y0, 0), box.w - 1);
    const int row = box.y + y0c;                 // 0..199
    *out_code = (r << 4) | py;
    return row * XBINS + (box.x >> 5);           // (row, x/32)
}

// Counting sort of each XCD's 896 items by (image_row, x/32).
// One block per XCD; result perm[xcd*896 + s] = (r<<4)|py.
__global__ __launch_bounds__(256) void order_kernel(
    const int* __restrict__ rois, int* __restrict__ perm) {
    const int xcd = blockIdx.x;
    const int tid = threadIdx.x;
    __shared__ int hist[NBINS];
    __shared__ int cnt[NBINS];
    __shared__ int partial[256];

    for (int k = tid; k < NBINS; k += 256) { hist[k] = 0; cnt[k] = 0; }
    __syncthreads();

    for (int i = tid; i < ITEMS_PER_XCD; i += 256) {
        int code;
        atomicAdd(&hist[item_key(rois, xcd, i, &code)], 1);
    }
    __syncthreads();

    // Exclusive scan of hist[NBINS]: per-thread chunk sums + Hillis-Steele.
    const int b0 = tid * BINS_PER_THREAD;
    int lsum[BINS_PER_THREAD];
    int local = 0;
    for (int j = 0; j < BINS_PER_THREAD; ++j) {
        const int k = b0 + j;
        lsum[j] = local;
        if (k < NBINS) local += hist[k];
    }
    partial[tid] = local;
    __syncthreads();
    for (int off = 1; off < 256; off <<= 1) {
        const int add = (tid >= off) ? partial[tid - off] : 0;
        __syncthreads();
        partial[tid] += add;
        __syncthreads();
    }
    const int chunk_excl = partial[tid] - local;
    for (int j = 0; j < BINS_PER_THREAD; ++j) {
        const int k = b0 + j;
        if (k < NBINS) hist[k] = chunk_excl + lsum[j];
    }
    __syncthreads();

    for (int i = tid; i < ITEMS_PER_XCD; i += 256) {
        int code;
        const int key = item_key(rois, xcd, i, &code);
        const int pos = hist[key] + atomicAdd(&cnt[key], 1);
        perm[xcd * ITEMS_PER_XCD + pos] = code;
    }
}

// One block (256 threads) per (roi, py) row: 14 cells, each thread owns 4
// channels. ROI -> XCD confinement via blockIdx&7; within an XCD, blocks
// are consumed in row-sorted order (perm) so co-resident blocks read the
// same image rows -> cross-block sharing is captured in the 4 MiB L2.
__global__ __launch_bounds__(256) void roi_row_kernel(
    const float* __restrict__ img,   // (200,200,1024)
    const int*   __restrict__ rois,  // (512,4) x,y,w,h
    const int*   __restrict__ perm,  // sorted work list, or null
    float*       __restrict__ out)   // (512,14,14,1024)
{
    const int b = blockIdx.x;        // 0 .. 7167
    int r, py;
    if (perm) {
        const int code = perm[(b & (NUM_XCD - 1)) * ITEMS_PER_XCD + (b >> 3)];
        r  = code >> 4;
        py = code & 15;
    } else {
        const int xcd = b & (NUM_XCD - 1);
        const int s   = b >> 3;
        const int roi_in = s / POOL;
        py = s - roi_in * POOL;
        r  = xcd * ROIS_PER_XCD + roi_in;
    }

    const int4 box = ((const int4*)rois)[r];
    const int bx = box.x, by = box.y, bw = box.z, bh = box.w;

    // jnp f32 semantics: s = arange(POOL) * (dim / 14.0f)
    const float stepy = (float)bh / (float)POOL;
    const float stepx = (float)bw / (float)POOL;

    const float sy = (float)py * stepy;
    const int   y0 = (int)floorf(sy);
    const float wy = sy - (float)y0;
    const int y0c = min(max(y0, 0), bh - 1);
    const int y1c = min(max(y0 + 1, 0), bh - 1);

    const float* __restrict__ row0 = img + (size_t)(by + y0c) * IMG_W * IMG_C;
    const float* __restrict__ row1 = img + (size_t)(by + y1c) * IMG_W * IMG_C;

    const int c = threadIdx.x * 4;
    float* __restrict__ orow =
        out + ((size_t)r * (POOL * POOL) + (size_t)py * POOL) * IMG_C + c;

#pragma unroll
    for (int px = 0; px < POOL; ++px) {
        const float sx = (float)px * stepx;
        const int   x0 = (int)floorf(sx);
        const float wx = sx - (float)x0;
        const int x0c = min(max(x0, 0), bw - 1);
        const int x1c = min(max(x0 + 1, 0), bw - 1);
        const int ix0 = bx + x0c;
        const int ix1 = bx + x1c;

        const v4f g00 = *(const v4f*)(row0 + (size_t)ix0 * IMG_C + c);
        const v4f g01 = *(const v4f*)(row0 + (size_t)ix1 * IMG_C + c);
        const v4f g10 = *(const v4f*)(row1 + (size_t)ix0 * IMG_C + c);
        const v4f g11 = *(const v4f*)(row1 + (size_t)ix1 * IMG_C + c);

        const v4f top = g00 + (g01 - g00) * wx;
        const v4f bot = g10 + (g11 - g10) * wx;
        const v4f res = top + (bot - top) * wy;

        // Write-once stream: non-temporal keeps it out of L1/L2.
        __builtin_nontemporal_store(res, (v4f*)(orow + (size_t)px * IMG_C));
    }
}

extern "C" void kernel_launch(void* const* d_in, const int* in_sizes, int n_in,
                              void* d_out, int out_size, void* d_ws, size_t ws_size,
                              hipStream_t stream) {
    const float* img  = (const float*)d_in[0];
    const int*   rois = (const int*)d_in[1];
    float*       out  = (float*)d_out;

    int* perm = nullptr;
    if (d_ws && ws_size >= (size_t)(NUM_XCD * ITEMS_PER_XCD) * sizeof(int)) {
        perm = (int*)d_ws;
        order_kernel<<<NUM_XCD, 256, 0, stream>>>(rois, perm);
    }
    roi_row_kernel<<<NUM_ROIS * POOL, 256, 0, stream>>>(img, rois, perm, out);
}